// Round 1
// baseline (381.497 us; speedup 1.0000x reference)
//
#include <hip/hip_runtime.h>
#include <hip/hip_bf16.h>

// CausalSelfAttention on MI355X (gfx950)
// x[4,2048,1024] f32, Wq/Wk/Wv/Wo [1024,1024] f32 -> out [4,2048,1024] f32
// Pipeline: cast->bf16, fused QKV GEMM (MFMA), flash attention, out-proj GEMM.

typedef __bf16 bf16_t;
typedef __bf16 bf16x8 __attribute__((ext_vector_type(8)));
typedef float  f32x4  __attribute__((ext_vector_type(4)));

#define MFMA16(a, b, c) __builtin_amdgcn_mfma_f32_16x16x32_bf16(a, b, c, 0, 0, 0)

__device__ __forceinline__ void gload_lds16(const bf16_t* g, bf16_t* l) {
    __builtin_amdgcn_global_load_lds(
        (const __attribute__((address_space(1))) void*)g,
        (__attribute__((address_space(3))) void*)l, 16, 0, 0);
}

// ---------------------------------------------------------------- casts
__global__ __launch_bounds__(256)
void cast_f32_bf16(const float* __restrict__ in, bf16_t* __restrict__ out, int n8) {
    int i = blockIdx.x * 256 + threadIdx.x;
    if (i >= n8) return;
    const float4* p = (const float4*)in;
    float4 a = p[i * 2], b = p[i * 2 + 1];
    bf16x8 o;
    o[0] = (bf16_t)a.x; o[1] = (bf16_t)a.y; o[2] = (bf16_t)a.z; o[3] = (bf16_t)a.w;
    o[4] = (bf16_t)b.x; o[5] = (bf16_t)b.y; o[6] = (bf16_t)b.z; o[7] = (bf16_t)b.w;
    *(bf16x8*)(out + (size_t)i * 8) = o;
}

__global__ __launch_bounds__(256)
void cast4_f32_bf16(const float* __restrict__ i0, const float* __restrict__ i1,
                    const float* __restrict__ i2, const float* __restrict__ i3,
                    bf16_t* o0, bf16_t* o1, bf16_t* o2, bf16_t* o3, int n8) {
    const float* in = blockIdx.y == 0 ? i0 : blockIdx.y == 1 ? i1 : blockIdx.y == 2 ? i2 : i3;
    bf16_t*     out = blockIdx.y == 0 ? o0 : blockIdx.y == 1 ? o1 : blockIdx.y == 2 ? o2 : o3;
    int i = blockIdx.x * 256 + threadIdx.x;
    if (i >= n8) return;
    const float4* p = (const float4*)in;
    float4 a = p[i * 2], b = p[i * 2 + 1];
    bf16x8 o;
    o[0] = (bf16_t)a.x; o[1] = (bf16_t)a.y; o[2] = (bf16_t)a.z; o[3] = (bf16_t)a.w;
    o[4] = (bf16_t)b.x; o[5] = (bf16_t)b.y; o[6] = (bf16_t)b.z; o[7] = (bf16_t)b.w;
    *(bf16x8*)(out + (size_t)i * 8) = o;
}

// ---------------------------------------------------------------- GEMM (C = A * B^T)
// A [M,K] bf16 row-major, B [N,K] bf16 row-major. m97 structure: 128x128 tile,
// BK=32, 4 waves of 64x64, global_load_lds width-16, linear LDS.
template<int OUT_BF16>
__global__ __launch_bounds__(256)
void gemm_bt(const bf16_t* __restrict__ A, const bf16_t* __restrict__ B,
             void* __restrict__ Cv, int M, int N, int K) {
    __shared__ bf16_t As[128 * 32];
    __shared__ bf16_t Bs[128 * 32];
    const int tid = threadIdx.x;
    const int lane = tid & 63;
    const int w = tid >> 6;
    const int wm = w >> 1, wn = w & 1;
    const int g = lane >> 4, c = lane & 15;
    const long bm = (long)blockIdx.x * 128;
    const long bn = (long)blockIdx.y * 128;

    f32x4 acc[4][4] = {};

    const int srow = tid >> 2;            // 0..63
    const int scol = (tid & 3) << 3;      // 0,8,16,24
    const bf16_t* Ag = A + (bm + srow) * (long)K + scol;
    const bf16_t* Bg = B + (bn + srow) * (long)K + scol;
    bf16_t* AsW = As + tid * 8;
    bf16_t* BsW = Bs + tid * 8;

    for (int k0 = 0; k0 < K; k0 += 32) {
        gload_lds16(Ag + k0,                 AsW);
        gload_lds16(Ag + k0 + (long)64 * K,  AsW + 2048);
        gload_lds16(Bg + k0,                 BsW);
        gload_lds16(Bg + k0 + (long)64 * K,  BsW + 2048);
        __syncthreads();
        bf16x8 af[4], bfr[4];
        #pragma unroll
        for (int m = 0; m < 4; ++m)
            af[m] = *(const bf16x8*)(As + (wm * 64 + m * 16 + c) * 32 + g * 8);
        #pragma unroll
        for (int n = 0; n < 4; ++n)
            bfr[n] = *(const bf16x8*)(Bs + (wn * 64 + n * 16 + c) * 32 + g * 8);
        #pragma unroll
        for (int m = 0; m < 4; ++m)
            #pragma unroll
            for (int n = 0; n < 4; ++n)
                acc[m][n] = MFMA16(af[m], bfr[n], acc[m][n]);
        __syncthreads();
    }
    #pragma unroll
    for (int m = 0; m < 4; ++m)
        #pragma unroll
        for (int n = 0; n < 4; ++n)
            #pragma unroll
            for (int i = 0; i < 4; ++i) {
                long row = bm + wm * 64 + m * 16 + g * 4 + i;  // D: row=(lane>>4)*4+reg
                long col = bn + wn * 64 + n * 16 + c;          // D: col=lane&15
                float v = acc[m][n][i];
                if (OUT_BF16) ((bf16_t*)Cv)[row * N + col] = (bf16_t)v;
                else          ((float*)Cv)[row * N + col]  = v;
            }
}

// ---------------------------------------------------------------- flash attention
// grid: (T/64, B*H). 4 waves x 16 q-rows. KV tile = 64. ldqkv=3072, ldo=1024.
__global__ __launch_bounds__(256)
void attn_kernel(const bf16_t* __restrict__ Qp, const bf16_t* __restrict__ Kp,
                 const bf16_t* __restrict__ Vp, bf16_t* __restrict__ O) {
    __shared__ bf16_t Ks[64 * 64];      // K[key][d], d-blocks XOR-swizzled by (key&7)
    __shared__ bf16_t Vts[64 * 64];     // V^T[d][key], key XOR-swizzled by ((d^(d>>3))&7)
    __shared__ bf16_t Ps[4 * 16 * 64];  // per-wave P[q][key], key swizzled by (q&7)

    const int tid = threadIdx.x, lane = tid & 63, w = tid >> 6;
    const int g = lane >> 4, c = lane & 15;
    const int qt = blockIdx.x;
    const int bh = blockIdx.y;
    const int b = bh >> 4, h = bh & 15;
    const int T = 2048, LDQ = 3072, LDO = 1024;
    const long rowbase = (long)b * T;
    const int hcol = h * 64;

    // Q fragments in registers for the whole block; fold 1/sqrt(64)=0.125 into Q.
    const int qrow = qt * 64 + w * 16 + c;  // A-frag: row = lane&15
    bf16x8 qf[2];
    #pragma unroll
    for (int ks = 0; ks < 2; ++ks) {
        qf[ks] = *(const bf16x8*)(Qp + (rowbase + qrow) * LDQ + hcol + ks * 32 + g * 8);
        #pragma unroll
        for (int j = 0; j < 8; ++j)
            qf[ks][j] = (bf16_t)((float)qf[ks][j] * 0.125f);
    }

    float m_r[4], l_r[4];
    #pragma unroll
    for (int i = 0; i < 4; ++i) { m_r[i] = -1e30f; l_r[i] = 0.f; }
    f32x4 acc_o[4] = {};  // [d-tile]; rows g*4+i, col nt*16+c

    const int nkt = qt + 1;
    for (int kt = 0; kt < nkt; ++kt) {
        const int kb = kt * 64;
        // --- stage K via global_load_lds, source pre-swizzled (linear LDS dest)
        #pragma unroll
        for (int i = 0; i < 2; ++i) {
            int row = i * 32 + (tid >> 3);          // key in tile
            int pb  = tid & 7;                      // physical d-block
            int lb  = pb ^ (row & 7);               // logical d-block at this slot
            gload_lds16(Kp + (rowbase + kb + row) * LDQ + hcol + lb * 8,
                        Ks + i * 2048 + tid * 8);
        }
        // --- stage V transposed (reg -> swizzled ds_write_b16)
        #pragma unroll
        for (int i = 0; i < 2; ++i) {
            int key = i * 32 + (tid >> 3);
            int d0  = (tid & 7) * 8;
            bf16x8 v8 = *(const bf16x8*)(Vp + (rowbase + kb + key) * LDQ + hcol + d0);
            #pragma unroll
            for (int j = 0; j < 8; ++j) {
                int d = d0 + j;
                int sw = (d ^ (d >> 3)) & 7;
                Vts[d * 64 + (key ^ (sw << 3))] = v8[j];
            }
        }
        __syncthreads();

        // --- S = Q K^T (rows q_local = g*4+i, cols key = kb + nt*16 + c)
        f32x4 sacc[4] = {};
        #pragma unroll
        for (int nt = 0; nt < 4; ++nt)
            #pragma unroll
            for (int ks = 0; ks < 2; ++ks) {
                int row = nt * 16 + c;
                int blk = (ks * 4 + g) ^ (row & 7);
                bf16x8 kf = *(const bf16x8*)(Ks + row * 64 + blk * 8);
                sacc[nt] = MFMA16(qf[ks], kf, sacc[nt]);
            }

        if (kt == qt) {  // diagonal tile: causal mask
            #pragma unroll
            for (int nt = 0; nt < 4; ++nt)
                #pragma unroll
                for (int i = 0; i < 4; ++i) {
                    int key = kb + nt * 16 + c;
                    int q   = qt * 64 + w * 16 + g * 4 + i;
                    if (key > q) sacc[nt][i] = -1e30f;
                }
        }

        // --- online softmax (16-lane groups share rows g*4+i)
        float mx[4];
        #pragma unroll
        for (int i = 0; i < 4; ++i)
            mx[i] = fmaxf(fmaxf(sacc[0][i], sacc[1][i]), fmaxf(sacc[2][i], sacc[3][i]));
        #pragma unroll
        for (int d = 1; d < 16; d <<= 1)
            #pragma unroll
            for (int i = 0; i < 4; ++i)
                mx[i] = fmaxf(mx[i], __shfl_xor(mx[i], d, 64));

        float mnew[4], scl[4], rsum[4];
        #pragma unroll
        for (int i = 0; i < 4; ++i) {
            mnew[i] = fmaxf(m_r[i], mx[i]);
            scl[i]  = __expf(m_r[i] - mnew[i]);
            rsum[i] = 0.f;
        }
        float pv[4][4];
        #pragma unroll
        for (int nt = 0; nt < 4; ++nt)
            #pragma unroll
            for (int i = 0; i < 4; ++i) {
                float p = __expf(sacc[nt][i] - mnew[i]);
                pv[nt][i] = p;
                rsum[i] += p;
            }
        #pragma unroll
        for (int d = 1; d < 16; d <<= 1)
            #pragma unroll
            for (int i = 0; i < 4; ++i)
                rsum[i] += __shfl_xor(rsum[i], d, 64);
        #pragma unroll
        for (int i = 0; i < 4; ++i) {
            l_r[i] = l_r[i] * scl[i] + rsum[i];
            m_r[i] = mnew[i];
        }
        #pragma unroll
        for (int nt = 0; nt < 4; ++nt)
            #pragma unroll
            for (int i = 0; i < 4; ++i)
                acc_o[nt][i] *= scl[i];

        // --- P -> LDS (bf16, swizzled), then barrier, then PV
        bf16_t* pw = Ps + w * 1024;
        #pragma unroll
        for (int nt = 0; nt < 4; ++nt)
            #pragma unroll
            for (int i = 0; i < 4; ++i) {
                int q = g * 4 + i;
                int col = nt * 16 + c;
                pw[q * 64 + (col ^ ((q & 7) << 3))] = (bf16_t)pv[nt][i];
            }
        __syncthreads();

        #pragma unroll
        for (int ks = 0; ks < 2; ++ks) {
            int kk = ks * 32;
            // A-frag: P[q=c][k = kk + g*8 + j]
            bf16x8 pf = *(const bf16x8*)(pw + c * 64 + ((kk + g * 8) ^ ((c & 7) << 3)));
            #pragma unroll
            for (int nt = 0; nt < 4; ++nt) {
                int dd = nt * 16 + c;
                int sw = (dd ^ (dd >> 3)) & 7;
                bf16x8 vf = *(const bf16x8*)(Vts + dd * 64 + ((kk + g * 8) ^ (sw << 3)));
                acc_o[nt] = MFMA16(pf, vf, acc_o[nt]);
            }
        }
        __syncthreads();  // before next tile's staging overwrites Ks/Vts
    }

    // --- epilogue: normalize, store bf16
    #pragma unroll
    for (int nt = 0; nt < 4; ++nt)
        #pragma unroll
        for (int i = 0; i < 4; ++i) {
            int q = qt * 64 + w * 16 + g * 4 + i;
            float val = acc_o[nt][i] / l_r[i];
            O[(rowbase + q) * LDO + hcol + nt * 16 + c] = (bf16_t)val;
        }
}

// ---------------------------------------------------------------- launch
extern "C" void kernel_launch(void* const* d_in, const int* in_sizes, int n_in,
                              void* d_out, int out_size, void* d_ws, size_t ws_size,
                              hipStream_t stream) {
    const float* x  = (const float*)d_in[0];
    const float* Wq = (const float*)d_in[1];
    const float* Wk = (const float*)d_in[2];
    const float* Wv = (const float*)d_in[3];
    const float* Wo = (const float*)d_in[4];

    const int M = 8192;       // B*T
    const int C = 1024;

    char* ws = (char*)d_ws;
    bf16_t* xb   = (bf16_t*)(ws);                          // 16 MB
    bf16_t* wqkv = (bf16_t*)(ws + ((size_t)16 << 20));     //  6 MB ([3072][1024])
    bf16_t* wob  = (bf16_t*)(ws + ((size_t)22 << 20));     //  2 MB
    bf16_t* qkv  = (bf16_t*)(ws + ((size_t)24 << 20));     // 48 MB ([8192][3072])
    bf16_t* aob  = (bf16_t*)(ws + ((size_t)72 << 20));     // 16 MB ([8192][1024])

    cast_f32_bf16<<<(M * C / 8) / 256, 256, 0, stream>>>(x, xb, M * C / 8);
    cast4_f32_bf16<<<dim3((C * C / 8) / 256, 4), 256, 0, stream>>>(
        Wq, Wk, Wv, Wo,
        wqkv, wqkv + (size_t)(C * C), wqkv + (size_t)(2 * C * C), wob, C * C / 8);

    // fused QKV projection: [8192,1024] x [3072,1024]^T -> [8192,3072] bf16
    gemm_bt<1><<<dim3(M / 128, 3072 / 128), 256, 0, stream>>>(xb, wqkv, qkv, M, 3072, C);

    // flash attention: Q/K/V interleaved in qkv with ld=3072
    attn_kernel<<<dim3(2048 / 64, 4 * 16), 256, 0, stream>>>(
        qkv, qkv + 1024, qkv + 2048, aob);

    // output projection -> fp32 d_out
    gemm_bt<0><<<dim3(M / 128, C / 128), 256, 0, stream>>>(aob, wob, d_out, M, C, C);
}

// Round 2
// 334.303 us; speedup vs baseline: 1.1412x; 1.1412x over previous
//
#include <hip/hip_runtime.h>
#include <hip/hip_bf16.h>

// CausalSelfAttention on MI355X (gfx950)
// x[4,2048,1024] f32, Wq/Wk/Wv/Wo [1024,1024] f32 -> out [4,2048,1024] f32
// Pipeline: cast->bf16, fused QKV GEMM (MFMA), flash attention, out-proj GEMM.

typedef __bf16 bf16_t;
typedef __bf16 bf16x8 __attribute__((ext_vector_type(8)));
typedef float  f32x4  __attribute__((ext_vector_type(4)));

#define MFMA16(a, b, c) __builtin_amdgcn_mfma_f32_16x16x32_bf16(a, b, c, 0, 0, 0)

__device__ __forceinline__ void gload_lds16(const bf16_t* g, bf16_t* l) {
    __builtin_amdgcn_global_load_lds(
        (const __attribute__((address_space(1))) void*)g,
        (__attribute__((address_space(3))) void*)l, 16, 0, 0);
}

// ---------------------------------------------------------------- casts
__global__ __launch_bounds__(256)
void cast_f32_bf16(const float* __restrict__ in, bf16_t* __restrict__ out, int n8) {
    int i = blockIdx.x * 256 + threadIdx.x;
    if (i >= n8) return;
    const float4* p = (const float4*)in;
    float4 a = p[i * 2], b = p[i * 2 + 1];
    bf16x8 o;
    o[0] = (bf16_t)a.x; o[1] = (bf16_t)a.y; o[2] = (bf16_t)a.z; o[3] = (bf16_t)a.w;
    o[4] = (bf16_t)b.x; o[5] = (bf16_t)b.y; o[6] = (bf16_t)b.z; o[7] = (bf16_t)b.w;
    *(bf16x8*)(out + (size_t)i * 8) = o;
}

__global__ __launch_bounds__(256)
void cast4_f32_bf16(const float* __restrict__ i0, const float* __restrict__ i1,
                    const float* __restrict__ i2, const float* __restrict__ i3,
                    bf16_t* o0, bf16_t* o1, bf16_t* o2, bf16_t* o3, int n8) {
    const float* in = blockIdx.y == 0 ? i0 : blockIdx.y == 1 ? i1 : blockIdx.y == 2 ? i2 : i3;
    bf16_t*     out = blockIdx.y == 0 ? o0 : blockIdx.y == 1 ? o1 : blockIdx.y == 2 ? o2 : o3;
    int i = blockIdx.x * 256 + threadIdx.x;
    if (i >= n8) return;
    const float4* p = (const float4*)in;
    float4 a = p[i * 2], b = p[i * 2 + 1];
    bf16x8 o;
    o[0] = (bf16_t)a.x; o[1] = (bf16_t)a.y; o[2] = (bf16_t)a.z; o[3] = (bf16_t)a.w;
    o[4] = (bf16_t)b.x; o[5] = (bf16_t)b.y; o[6] = (bf16_t)b.z; o[7] = (bf16_t)b.w;
    *(bf16x8*)(out + (size_t)i * 8) = o;
}

// ---------------------------------------------------------------- GEMM (C = A * B^T)
template<int OUT_BF16>
__global__ __launch_bounds__(256)
void gemm_bt(const bf16_t* __restrict__ A, const bf16_t* __restrict__ B,
             void* __restrict__ Cv, int M, int N, int K) {
    __shared__ bf16_t As[128 * 32];
    __shared__ bf16_t Bs[128 * 32];
    const int tid = threadIdx.x;
    const int lane = tid & 63;
    const int w = tid >> 6;
    const int wm = w >> 1, wn = w & 1;
    const int g = lane >> 4, c = lane & 15;
    const long bm = (long)blockIdx.x * 128;
    const long bn = (long)blockIdx.y * 128;

    f32x4 acc[4][4] = {};

    const int srow = tid >> 2;
    const int scol = (tid & 3) << 3;
    const bf16_t* Ag = A + (bm + srow) * (long)K + scol;
    const bf16_t* Bg = B + (bn + srow) * (long)K + scol;
    bf16_t* AsW = As + tid * 8;
    bf16_t* BsW = Bs + tid * 8;

    for (int k0 = 0; k0 < K; k0 += 32) {
        gload_lds16(Ag + k0,                 AsW);
        gload_lds16(Ag + k0 + (long)64 * K,  AsW + 2048);
        gload_lds16(Bg + k0,                 BsW);
        gload_lds16(Bg + k0 + (long)64 * K,  BsW + 2048);
        __syncthreads();
        bf16x8 af[4], bfr[4];
        #pragma unroll
        for (int m = 0; m < 4; ++m)
            af[m] = *(const bf16x8*)(As + (wm * 64 + m * 16 + c) * 32 + g * 8);
        #pragma unroll
        for (int n = 0; n < 4; ++n)
            bfr[n] = *(const bf16x8*)(Bs + (wn * 64 + n * 16 + c) * 32 + g * 8);
        #pragma unroll
        for (int m = 0; m < 4; ++m)
            #pragma unroll
            for (int n = 0; n < 4; ++n)
                acc[m][n] = MFMA16(af[m], bfr[n], acc[m][n]);
        __syncthreads();
    }
    #pragma unroll
    for (int m = 0; m < 4; ++m)
        #pragma unroll
        for (int n = 0; n < 4; ++n)
            #pragma unroll
            for (int i = 0; i < 4; ++i) {
                long row = bm + wm * 64 + m * 16 + g * 4 + i;
                long col = bn + wn * 64 + n * 16 + c;
                float v = acc[m][n][i];
                if (OUT_BF16) ((bf16_t*)Cv)[row * N + col] = (bf16_t)v;
                else          ((float*)Cv)[row * N + col]  = v;
            }
}

// ---------------------------------------------------------------- flash attention
// grid: (16, B*H). 4 waves x 32 q-rows = 128 q-rows/block. KV tile = 64,
// double-buffered. 1 barrier per tile. ld(qkv)=3072, ld(o)=1024.

__device__ __forceinline__ void stage_K(const bf16_t* Kp, long rowb, int kb, int hcol,
                                        bf16_t* Kbuf, int tid) {
    #pragma unroll
    for (int i = 0; i < 2; ++i) {
        int row = i * 32 + (tid >> 3);
        int lb  = (tid & 7) ^ (row & 7);          // pre-swizzled source -> linear LDS
        gload_lds16(Kp + (rowb + kb + row) * 3072 + hcol + lb * 8,
                    Kbuf + i * 2048 + tid * 8);
    }
}

__device__ __forceinline__ void load_V(const bf16_t* Vp, long rowb, int kb, int hcol,
                                       int tid, unsigned int* vr) {
    const int d0 = (tid & 31) * 2;
    const int k0 = (tid >> 5) * 8;
    const unsigned int* src =
        (const unsigned int*)(Vp + (rowb + kb + k0) * 3072 + hcol + d0);
    #pragma unroll
    for (int i = 0; i < 8; ++i) vr[i] = src[(size_t)i * 1536];
}

__device__ __forceinline__ void write_Vt(bf16_t* Vbuf, int tid, const unsigned int* vr) {
    const int d0 = (tid & 31) * 2;
    const int k0 = (tid >> 5) * 8;
    unsigned int lo[4], hi[4];
    #pragma unroll
    for (int i = 0; i < 4; ++i) {
        lo[i] = (vr[2 * i] & 0xffffu) | (vr[2 * i + 1] << 16);
        hi[i] = (vr[2 * i] >> 16)     | (vr[2 * i + 1] & 0xffff0000u);
    }
    *(uint4*)&Vbuf[(d0 + 0) * 72 + k0] = make_uint4(lo[0], lo[1], lo[2], lo[3]);
    *(uint4*)&Vbuf[(d0 + 1) * 72 + k0] = make_uint4(hi[0], hi[1], hi[2], hi[3]);
}

__global__ __launch_bounds__(256)
void attn_kernel(const bf16_t* __restrict__ Qp, const bf16_t* __restrict__ Kp,
                 const bf16_t* __restrict__ Vp, bf16_t* __restrict__ O) {
    __shared__ bf16_t Ks[2][64 * 64];    // K[key][d], d-blocks XOR-swizzled by key&7
    __shared__ bf16_t Vts[2][64 * 72];   // V^T[d][key], stride 72 (pad kills conflicts)
    __shared__ bf16_t Ps[4][32 * 64];    // per-wave P[q][key], key XOR-swizzled by q&7

    const int tid = threadIdx.x, lane = tid & 63, w = tid >> 6;
    const int g = lane >> 4, c = lane & 15;
    const int q0 = 15 - blockIdx.x;               // big blocks dispatch first
    const int bh = blockIdx.y, b = bh >> 4, h = bh & 15;
    const int LDQ = 3072, LDO = 1024;
    const long rowb = (long)b * 2048;
    const int hcol = h * 64;
    const int qlo = q0 * 128 + w * 32;            // this wave's 32 q-rows

    // Q fragments (scale 1/8 folded in)
    bf16x8 qf[2][2];
    #pragma unroll
    for (int m = 0; m < 2; ++m)
        #pragma unroll
        for (int ks = 0; ks < 2; ++ks) {
            qf[m][ks] = *(const bf16x8*)(Qp + (rowb + qlo + m * 16 + c) * LDQ +
                                         hcol + ks * 32 + g * 8);
            #pragma unroll
            for (int j = 0; j < 8; ++j)
                qf[m][ks][j] = (bf16_t)((float)qf[m][ks][j] * 0.125f);
        }

    float m_r[2][4], l_r[2][4];
    #pragma unroll
    for (int m = 0; m < 2; ++m)
        #pragma unroll
        for (int i = 0; i < 4; ++i) { m_r[m][i] = -1e30f; l_r[m][i] = 0.f; }
    f32x4 acc[2][4] = {};

    const int nkt = 2 * q0 + 2;

    // prologue: stage tile 0
    stage_K(Kp, rowb, 0, hcol, Ks[0], tid);
    {
        unsigned int vr0[8];
        load_V(Vp, rowb, 0, hcol, tid, vr0);
        write_Vt(Vts[0], tid, vr0);
    }
    __syncthreads();

    for (int t = 0; t < nkt; ++t) {
        const int cur = t & 1;
        const int kb = t * 64;
        const bool pre = (t + 1 < nkt);
        unsigned int vr[8];
        if (pre) {                                 // issue next tile early
            stage_K(Kp, rowb, kb + 64, hcol, Ks[cur ^ 1], tid);
            load_V(Vp, rowb, kb + 64, hcol, tid, vr);
        }

        if (kb <= qlo + 31) {                      // skip fully-masked tiles (per-wave)
            // --- S = Q K^T
            f32x4 sacc[2][4] = {};
            #pragma unroll
            for (int nt = 0; nt < 4; ++nt) {
                const int row = nt * 16 + c;
                #pragma unroll
                for (int ks = 0; ks < 2; ++ks) {
                    bf16x8 kf = *(const bf16x8*)&Ks[cur][row * 64 +
                                    (((ks * 4 + g) ^ (row & 7)) * 8)];
                    sacc[0][nt] = MFMA16(qf[0][ks], kf, sacc[0][nt]);
                    sacc[1][nt] = MFMA16(qf[1][ks], kf, sacc[1][nt]);
                }
            }
            if (kb + 63 > qlo) {                   // diagonal: causal mask
                #pragma unroll
                for (int m = 0; m < 2; ++m)
                    #pragma unroll
                    for (int nt = 0; nt < 4; ++nt)
                        #pragma unroll
                        for (int i = 0; i < 4; ++i) {
                            int key = kb + nt * 16 + c;
                            int q   = qlo + m * 16 + g * 4 + i;
                            if (key > q) sacc[m][nt][i] = -1e30f;
                        }
            }
            // --- online softmax (reduce across the 16 lanes of each group)
            float scl[2][4];
            float pvv[2][4][4];
            #pragma unroll
            for (int m = 0; m < 2; ++m) {
                float mx[4], rsum[4];
                #pragma unroll
                for (int i = 0; i < 4; ++i)
                    mx[i] = fmaxf(fmaxf(sacc[m][0][i], sacc[m][1][i]),
                                  fmaxf(sacc[m][2][i], sacc[m][3][i]));
                #pragma unroll
                for (int d = 1; d < 16; d <<= 1)
                    #pragma unroll
                    for (int i = 0; i < 4; ++i)
                        mx[i] = fmaxf(mx[i], __shfl_xor(mx[i], d, 64));
                #pragma unroll
                for (int i = 0; i < 4; ++i) {
                    float mnew = fmaxf(m_r[m][i], mx[i]);
                    scl[m][i]  = __expf(m_r[m][i] - mnew);
                    m_r[m][i]  = mnew;
                    rsum[i]    = 0.f;
                }
                #pragma unroll
                for (int nt = 0; nt < 4; ++nt)
                    #pragma unroll
                    for (int i = 0; i < 4; ++i) {
                        float p = __expf(sacc[m][nt][i] - m_r[m][i]);
                        pvv[m][nt][i] = p;
                        rsum[i] += p;
                    }
                #pragma unroll
                for (int d = 1; d < 16; d <<= 1)
                    #pragma unroll
                    for (int i = 0; i < 4; ++i)
                        rsum[i] += __shfl_xor(rsum[i], d, 64);
                #pragma unroll
                for (int i = 0; i < 4; ++i)
                    l_r[m][i] = l_r[m][i] * scl[m][i] + rsum[i];
            }
            #pragma unroll
            for (int m = 0; m < 2; ++m)
                #pragma unroll
                for (int nt = 0; nt < 4; ++nt)
                    #pragma unroll
                    for (int i = 0; i < 4; ++i)
                        acc[m][nt][i] *= scl[m][i];

            // --- P -> wave-private LDS (no barrier needed), then PV
            bf16_t* pw = Ps[w];
            #pragma unroll
            for (int m = 0; m < 2; ++m)
                #pragma unroll
                for (int nt = 0; nt < 4; ++nt)
                    #pragma unroll
                    for (int i = 0; i < 4; ++i) {
                        int qq  = m * 16 + g * 4 + i;
                        int col = nt * 16 + c;
                        pw[qq * 64 + (col ^ ((qq & 7) << 3))] = (bf16_t)pvv[m][nt][i];
                    }
            #pragma unroll
            for (int ks = 0; ks < 2; ++ks) {
                bf16x8 pf0 = *(const bf16x8*)&pw[(c)      * 64 +
                                 ((ks * 32 + g * 8) ^ ((c & 7) << 3))];
                bf16x8 pf1 = *(const bf16x8*)&pw[(16 + c) * 64 +
                                 ((ks * 32 + g * 8) ^ ((c & 7) << 3))];
                #pragma unroll
                for (int nt = 0; nt < 4; ++nt) {
                    bf16x8 vf = *(const bf16x8*)&Vts[cur][(nt * 16 + c) * 72 +
                                                          ks * 32 + g * 8];
                    acc[0][nt] = MFMA16(pf0, vf, acc[0][nt]);
                    acc[1][nt] = MFMA16(pf1, vf, acc[1][nt]);
                }
            }
        }

        if (pre) write_Vt(Vts[cur ^ 1], tid, vr);  // write-late (T14)
        __syncthreads();                           // single barrier per tile
    }

    // --- epilogue
    #pragma unroll
    for (int m = 0; m < 2; ++m)
        #pragma unroll
        for (int nt = 0; nt < 4; ++nt)
            #pragma unroll
            for (int i = 0; i < 4; ++i) {
                int q = qlo + m * 16 + g * 4 + i;
                O[(rowb + q) * LDO + hcol + nt * 16 + c] =
                    (bf16_t)(acc[m][nt][i] / l_r[m][i]);
            }
}

// ---------------------------------------------------------------- launch
extern "C" void kernel_launch(void* const* d_in, const int* in_sizes, int n_in,
                              void* d_out, int out_size, void* d_ws, size_t ws_size,
                              hipStream_t stream) {
    const float* x  = (const float*)d_in[0];
    const float* Wq = (const float*)d_in[1];
    const float* Wk = (const float*)d_in[2];
    const float* Wv = (const float*)d_in[3];
    const float* Wo = (const float*)d_in[4];

    const int M = 8192;
    const int C = 1024;

    char* ws = (char*)d_ws;
    bf16_t* xb   = (bf16_t*)(ws);                          // 16 MB
    bf16_t* wqkv = (bf16_t*)(ws + ((size_t)16 << 20));     //  6 MB ([3072][1024])
    bf16_t* wob  = (bf16_t*)(ws + ((size_t)22 << 20));     //  2 MB
    bf16_t* qkv  = (bf16_t*)(ws + ((size_t)24 << 20));     // 48 MB ([8192][3072])
    bf16_t* aob  = (bf16_t*)(ws + ((size_t)72 << 20));     // 16 MB ([8192][1024])

    cast_f32_bf16<<<(M * C / 8) / 256, 256, 0, stream>>>(x, xb, M * C / 8);
    cast4_f32_bf16<<<dim3((C * C / 8) / 256, 4), 256, 0, stream>>>(
        Wq, Wk, Wv, Wo,
        wqkv, wqkv + (size_t)(C * C), wqkv + (size_t)(2 * C * C), wob, C * C / 8);

    gemm_bt<1><<<dim3(M / 128, 3072 / 128), 256, 0, stream>>>(xb, wqkv, qkv, M, 3072, C);

    attn_kernel<<<dim3(16, 4 * 16), 256, 0, stream>>>(
        qkv, qkv + 1024, qkv + 2048, aob);

    gemm_bt<0><<<dim3(M / 128, C / 128), 256, 0, stream>>>(aob, wob, d_out, M, C, C);
}

// Round 3
// 193.956 us; speedup vs baseline: 1.9669x; 1.7236x over previous
//
#include <hip/hip_runtime.h>
#include <hip/hip_bf16.h>

// CausalSelfAttention on MI355X (gfx950)
// x[4,2048,1024] f32, Wq/Wk/Wv/Wo [1024,1024] f32 -> out [4,2048,1024] f32
// Pipeline: cast->bf16, fused QKV GEMM (MFMA), flash attention, out-proj GEMM.

typedef __bf16 bf16_t;
typedef __bf16 bf16x4 __attribute__((ext_vector_type(4)));
typedef __bf16 bf16x8 __attribute__((ext_vector_type(8)));
typedef float  f32x4  __attribute__((ext_vector_type(4)));

#define MFMA16(a, b, c) __builtin_amdgcn_mfma_f32_16x16x32_bf16(a, b, c, 0, 0, 0)

__device__ __forceinline__ float exp2_(float x) {
#if __has_builtin(__builtin_amdgcn_exp2f)
    return __builtin_amdgcn_exp2f(x);
#else
    return __expf(x * 0.6931471805599453f);
#endif
}

__device__ __forceinline__ void gload_lds16(const bf16_t* g, bf16_t* l) {
    __builtin_amdgcn_global_load_lds(
        (const __attribute__((address_space(1))) void*)g,
        (__attribute__((address_space(3))) void*)l, 16, 0, 0);
}

// ---------------------------------------------------------------- casts
__global__ __launch_bounds__(256)
void cast_f32_bf16(const float* __restrict__ in, bf16_t* __restrict__ out, int n8) {
    int i = blockIdx.x * 256 + threadIdx.x;
    if (i >= n8) return;
    const float4* p = (const float4*)in;
    float4 a = p[i * 2], b = p[i * 2 + 1];
    bf16x8 o;
    o[0] = (bf16_t)a.x; o[1] = (bf16_t)a.y; o[2] = (bf16_t)a.z; o[3] = (bf16_t)a.w;
    o[4] = (bf16_t)b.x; o[5] = (bf16_t)b.y; o[6] = (bf16_t)b.z; o[7] = (bf16_t)b.w;
    *(bf16x8*)(out + (size_t)i * 8) = o;
}

__global__ __launch_bounds__(256)
void cast4_f32_bf16(const float* __restrict__ i0, const float* __restrict__ i1,
                    const float* __restrict__ i2, const float* __restrict__ i3,
                    bf16_t* o0, bf16_t* o1, bf16_t* o2, bf16_t* o3, int n8) {
    const float* in = blockIdx.y == 0 ? i0 : blockIdx.y == 1 ? i1 : blockIdx.y == 2 ? i2 : i3;
    bf16_t*     out = blockIdx.y == 0 ? o0 : blockIdx.y == 1 ? o1 : blockIdx.y == 2 ? o2 : o3;
    int i = blockIdx.x * 256 + threadIdx.x;
    if (i >= n8) return;
    const float4* p = (const float4*)in;
    float4 a = p[i * 2], b = p[i * 2 + 1];
    bf16x8 o;
    o[0] = (bf16_t)a.x; o[1] = (bf16_t)a.y; o[2] = (bf16_t)a.z; o[3] = (bf16_t)a.w;
    o[4] = (bf16_t)b.x; o[5] = (bf16_t)b.y; o[6] = (bf16_t)b.z; o[7] = (bf16_t)b.w;
    *(bf16x8*)(out + (size_t)i * 8) = o;
}

// ---------------------------------------------------------------- GEMM (C = A * B^T)
template<int OUT_BF16>
__global__ __launch_bounds__(256)
void gemm_bt(const bf16_t* __restrict__ A, const bf16_t* __restrict__ B,
             void* __restrict__ Cv, int M, int N, int K) {
    __shared__ bf16_t As[128 * 32];
    __shared__ bf16_t Bs[128 * 32];
    const int tid = threadIdx.x;
    const int lane = tid & 63;
    const int w = tid >> 6;
    const int wm = w >> 1, wn = w & 1;
    const int g = lane >> 4, c = lane & 15;
    const long bm = (long)blockIdx.x * 128;
    const long bn = (long)blockIdx.y * 128;

    f32x4 acc[4][4] = {};

    const int srow = tid >> 2;
    const int scol = (tid & 3) << 3;
    const bf16_t* Ag = A + (bm + srow) * (long)K + scol;
    const bf16_t* Bg = B + (bn + srow) * (long)K + scol;
    bf16_t* AsW = As + tid * 8;
    bf16_t* BsW = Bs + tid * 8;

    for (int k0 = 0; k0 < K; k0 += 32) {
        gload_lds16(Ag + k0,                 AsW);
        gload_lds16(Ag + k0 + (long)64 * K,  AsW + 2048);
        gload_lds16(Bg + k0,                 BsW);
        gload_lds16(Bg + k0 + (long)64 * K,  BsW + 2048);
        __syncthreads();
        bf16x8 af[4], bfr[4];
        #pragma unroll
        for (int m = 0; m < 4; ++m)
            af[m] = *(const bf16x8*)(As + (wm * 64 + m * 16 + c) * 32 + g * 8);
        #pragma unroll
        for (int n = 0; n < 4; ++n)
            bfr[n] = *(const bf16x8*)(Bs + (wn * 64 + n * 16 + c) * 32 + g * 8);
        #pragma unroll
        for (int m = 0; m < 4; ++m)
            #pragma unroll
            for (int n = 0; n < 4; ++n)
                acc[m][n] = MFMA16(af[m], bfr[n], acc[m][n]);
        __syncthreads();
    }
    #pragma unroll
    for (int m = 0; m < 4; ++m)
        #pragma unroll
        for (int n = 0; n < 4; ++n)
            #pragma unroll
            for (int i = 0; i < 4; ++i) {
                long row = bm + wm * 64 + m * 16 + g * 4 + i;
                long col = bn + wn * 64 + n * 16 + c;
                float v = acc[m][n][i];
                if (OUT_BF16) ((bf16_t*)Cv)[row * N + col] = (bf16_t)v;
                else          ((float*)Cv)[row * N + col]  = v;
            }
}

// ---------------------------------------------------------------- flash attention
// grid: (64=B*H, 8). Each block does q-tiles {bx, 15-bx} (34 kv-tiles total,
// uniform). 4 waves x 32 q-rows. Swapped QK^T: lane owns one q-row (col=c),
// softmax in-lane, P packed b64 into per-wave LDS, PV = mfma(V^T, P).

__device__ __forceinline__ void stage_K(const bf16_t* Kp, long rowb, int kb, int hcol,
                                        bf16_t* Kbuf, int tid) {
    #pragma unroll
    for (int i = 0; i < 2; ++i) {
        int row = i * 32 + (tid >> 3);
        int lb  = (tid & 7) ^ (row & 7);          // pre-swizzled source -> linear LDS
        gload_lds16(Kp + (rowb + kb + row) * 3072 + hcol + lb * 8,
                    Kbuf + i * 2048 + tid * 8);
    }
}

__device__ __forceinline__ void load_V(const bf16_t* Vp, long rowb, int kb, int hcol,
                                       int tid, unsigned int* vr) {
    const int d0 = (tid & 31) * 2;
    const int k0 = (tid >> 5) * 8;
    const unsigned int* src =
        (const unsigned int*)(Vp + (rowb + kb + k0) * 3072 + hcol + d0);
    #pragma unroll
    for (int i = 0; i < 8; ++i) vr[i] = src[(size_t)i * 1536];
}

__device__ __forceinline__ void write_Vt(bf16_t* Vbuf, int tid, const unsigned int* vr) {
    const int d0 = (tid & 31) * 2;
    const int k0 = (tid >> 5) * 8;
    unsigned int lo[4], hi[4];
    #pragma unroll
    for (int i = 0; i < 4; ++i) {
        lo[i] = (vr[2 * i] & 0xffffu) | (vr[2 * i + 1] << 16);
        hi[i] = (vr[2 * i] >> 16)     | (vr[2 * i + 1] & 0xffff0000u);
    }
    *(uint4*)&Vbuf[(d0 + 0) * 72 + k0] = make_uint4(lo[0], lo[1], lo[2], lo[3]);
    *(uint4*)&Vbuf[(d0 + 1) * 72 + k0] = make_uint4(hi[0], hi[1], hi[2], hi[3]);
}

__global__ __launch_bounds__(256)
void attn_kernel(const bf16_t* __restrict__ Qp, const bf16_t* __restrict__ Kp,
                 const bf16_t* __restrict__ Vp, bf16_t* __restrict__ O) {
    __shared__ bf16_t Ks[2][64 * 64];    // K[key][d], d-blocks XOR-swizzled by key&7
    __shared__ bf16_t Vts[2][64 * 72];   // V^T[d][key], stride 72
    __shared__ bf16_t PW[4][32 * 72];    // per-wave P[q][key], stride 72

    const int tid = threadIdx.x, lane = tid & 63, w = tid >> 6;
    const int g = lane >> 4, c = lane & 15;
    const int bh = blockIdx.x, bx = blockIdx.y;   // same-bh blocks share XCD (id%8)
    const int b = bh >> 4, h = bh & 15;
    const long rowb = (long)b * 2048;
    const int hcol = h * 64;
    const float QSCL = 0.18033688011112042f;      // 0.125 * log2(e)

    for (int pass = 0; pass < 2; ++pass) {
        const int q0  = pass ? (15 - bx) : bx;
        const int qlo = q0 * 128 + w * 32;        // this wave's 32 q-rows
        const int nkt = 2 * q0 + 2;

        // Q as B-fragments: lane holds Q[q = qlo+m*16+c][k = ks*32+g*8+j]
        bf16x8 qf[2][2];
        #pragma unroll
        for (int m = 0; m < 2; ++m)
            #pragma unroll
            for (int ks = 0; ks < 2; ++ks) {
                qf[m][ks] = *(const bf16x8*)(Qp + (rowb + qlo + m * 16 + c) * 3072 +
                                             hcol + ks * 32 + g * 8);
                #pragma unroll
                for (int j = 0; j < 8; ++j)
                    qf[m][ks][j] = (bf16_t)((float)qf[m][ks][j] * QSCL);
            }

        float m_r[2] = {-1e30f, -1e30f};
        float l_r[2] = {0.f, 0.f};
        f32x4 acc[2][4] = {};                     // O^T: [d-blk nt][rows g*4+i], col q=c

        stage_K(Kp, rowb, 0, hcol, Ks[0], tid);
        {
            unsigned int vr0[8];
            load_V(Vp, rowb, 0, hcol, tid, vr0);
            write_Vt(Vts[0], tid, vr0);
        }
        __syncthreads();

        for (int t = 0; t < nkt; ++t) {
            const int cur = t & 1;
            const int kb = t * 64;
            const bool pre = (t + 1 < nkt);
            unsigned int vr[8];
            if (pre) {
                stage_K(Kp, rowb, kb + 64, hcol, Ks[cur ^ 1], tid);
                load_V(Vp, rowb, kb + 64, hcol, tid, vr);
            }

            if (kb <= qlo + 31) {                 // skip fully-masked tiles (per-wave)
                // --- S^T = K Q^T: rows key = nt*16+g*4+i, col q = c
                f32x4 sacc[2][4] = {};
                #pragma unroll
                for (int nt = 0; nt < 4; ++nt) {
                    const int row = nt * 16 + c;
                    #pragma unroll
                    for (int ks = 0; ks < 2; ++ks) {
                        bf16x8 kf = *(const bf16x8*)&Ks[cur][row * 64 +
                                        (((ks * 4 + g) ^ (c & 7)) * 8)];
                        sacc[0][nt] = MFMA16(kf, qf[0][ks], sacc[0][nt]);
                        sacc[1][nt] = MFMA16(kf, qf[1][ks], sacc[1][nt]);
                    }
                }
                if (kb + 63 > qlo) {              // diagonal: causal mask
                    #pragma unroll
                    for (int m = 0; m < 2; ++m) {
                        const int q = qlo + m * 16 + c;
                        #pragma unroll
                        for (int nt = 0; nt < 4; ++nt)
                            #pragma unroll
                            for (int i = 0; i < 4; ++i) {
                                int key = kb + nt * 16 + g * 4 + i;
                                if (key > q) sacc[m][nt][i] = -1e30f;
                            }
                    }
                }

                // --- online softmax: each lane owns one q-row per m.
                float scl[2];
                #pragma unroll
                for (int m = 0; m < 2; ++m) {
                    float mx = sacc[m][0][0];
                    #pragma unroll
                    for (int nt = 0; nt < 4; ++nt)
                        #pragma unroll
                        for (int i = 0; i < 4; ++i)
                            mx = fmaxf(mx, sacc[m][nt][i]);
                    mx = fmaxf(mx, __shfl_xor(mx, 16, 64));
                    mx = fmaxf(mx, __shfl_xor(mx, 32, 64));
                    float mnew = fmaxf(m_r[m], mx);
                    scl[m] = exp2_(m_r[m] - mnew);
                    m_r[m] = mnew;
                    float rs = 0.f;
                    #pragma unroll
                    for (int nt = 0; nt < 4; ++nt)
                        #pragma unroll
                        for (int i = 0; i < 4; ++i) {
                            float pv = exp2_(sacc[m][nt][i] - mnew);
                            sacc[m][nt][i] = pv;
                            rs += pv;
                        }
                    rs += __shfl_xor(rs, 16, 64);
                    rs += __shfl_xor(rs, 32, 64);
                    l_r[m] = l_r[m] * scl[m] + rs;
                    // --- P pack: lane holds 4 consecutive keys -> one b64 per nt
                    #pragma unroll
                    for (int nt = 0; nt < 4; ++nt) {
                        bf16x4 t4;
                        #pragma unroll
                        for (int i = 0; i < 4; ++i) t4[i] = (bf16_t)sacc[m][nt][i];
                        *(bf16x4*)&PW[w][(m * 16 + c) * 72 + nt * 16 + g * 4] = t4;
                    }
                }
                #pragma unroll
                for (int m = 0; m < 2; ++m)
                    #pragma unroll
                    for (int nt = 0; nt < 4; ++nt)
                        acc[m][nt] *= scl[m];

                // --- PV: O^T = V^T P^T; A = V^T frag, B = P frag (wave-private LDS)
                #pragma unroll
                for (int ks = 0; ks < 2; ++ks) {
                    bf16x8 pf0 = *(const bf16x8*)&PW[w][(c)      * 72 + ks * 32 + g * 8];
                    bf16x8 pf1 = *(const bf16x8*)&PW[w][(16 + c) * 72 + ks * 32 + g * 8];
                    #pragma unroll
                    for (int nt = 0; nt < 4; ++nt) {
                        bf16x8 vf = *(const bf16x8*)&Vts[cur][(nt * 16 + c) * 72 +
                                                              ks * 32 + g * 8];
                        acc[0][nt] = MFMA16(vf, pf0, acc[0][nt]);
                        acc[1][nt] = MFMA16(vf, pf1, acc[1][nt]);
                    }
                }
            }

            if (pre) write_Vt(Vts[cur ^ 1], tid, vr);   // write-late (T14)
            __syncthreads();                             // single barrier per tile
        }

        // --- epilogue: O^T -> (via wave-private LDS transpose) coalesced O rows
        #pragma unroll
        for (int m = 0; m < 2; ++m) {
            float rl = __builtin_amdgcn_rcpf(l_r[m]);
            #pragma unroll
            for (int nt = 0; nt < 4; ++nt) {
                bf16x4 t4;
                #pragma unroll
                for (int i = 0; i < 4; ++i) t4[i] = (bf16_t)(acc[m][nt][i] * rl);
                *(bf16x4*)&PW[w][(m * 16 + c) * 72 + nt * 16 + g * 4] = t4;
            }
        }
        #pragma unroll
        for (int r0 = 0; r0 < 4; ++r0) {
            int row = r0 * 8 + (lane >> 3);
            int ch  = (lane & 7) * 8;
            bf16x8 v = *(const bf16x8*)&PW[w][row * 72 + ch];
            *(bf16x8*)&O[(rowb + qlo + row) * 1024 + hcol + ch] = v;
        }
    }
}

// ---------------------------------------------------------------- launch
extern "C" void kernel_launch(void* const* d_in, const int* in_sizes, int n_in,
                              void* d_out, int out_size, void* d_ws, size_t ws_size,
                              hipStream_t stream) {
    const float* x  = (const float*)d_in[0];
    const float* Wq = (const float*)d_in[1];
    const float* Wk = (const float*)d_in[2];
    const float* Wv = (const float*)d_in[3];
    const float* Wo = (const float*)d_in[4];

    const int M = 8192;
    const int C = 1024;

    char* ws = (char*)d_ws;
    bf16_t* xb   = (bf16_t*)(ws);                          // 16 MB
    bf16_t* wqkv = (bf16_t*)(ws + ((size_t)16 << 20));     //  6 MB ([3072][1024])
    bf16_t* wob  = (bf16_t*)(ws + ((size_t)22 << 20));     //  2 MB
    bf16_t* qkv  = (bf16_t*)(ws + ((size_t)24 << 20));     // 48 MB ([8192][3072])
    bf16_t* aob  = (bf16_t*)(ws + ((size_t)72 << 20));     // 16 MB ([8192][1024])

    cast_f32_bf16<<<(M * C / 8) / 256, 256, 0, stream>>>(x, xb, M * C / 8);
    cast4_f32_bf16<<<dim3((C * C / 8) / 256, 4), 256, 0, stream>>>(
        Wq, Wk, Wv, Wo,
        wqkv, wqkv + (size_t)(C * C), wqkv + (size_t)(2 * C * C), wob, C * C / 8);

    gemm_bt<1><<<dim3(M / 128, 3072 / 128), 256, 0, stream>>>(xb, wqkv, qkv, M, 3072, C);

    attn_kernel<<<dim3(64, 8), 256, 0, stream>>>(
        qkv, qkv + 1024, qkv + 2048, aob);

    gemm_bt<0><<<dim3(M / 128, C / 128), 256, 0, stream>>>(aob, wob, d_out, M, C, C);
}

// Round 4
// 187.928 us; speedup vs baseline: 2.0300x; 1.0321x over previous
//
#include <hip/hip_runtime.h>
#include <hip/hip_bf16.h>

// CausalSelfAttention on MI355X (gfx950)
// x[4,2048,1024] f32, Wq/Wk/Wv/Wo [1024,1024] f32 -> out [4,2048,1024] f32
// Pipeline: cast->bf16, fused QKV GEMM (MFMA), flash attention, out-proj GEMM.

typedef __bf16 bf16_t;
typedef __bf16 bf16x4 __attribute__((ext_vector_type(4)));
typedef __bf16 bf16x8 __attribute__((ext_vector_type(8)));
typedef float  f32x4  __attribute__((ext_vector_type(4)));

#define MFMA16(a, b, c) __builtin_amdgcn_mfma_f32_16x16x32_bf16(a, b, c, 0, 0, 0)

__device__ __forceinline__ float exp2_(float x) {
#if __has_builtin(__builtin_amdgcn_exp2f)
    return __builtin_amdgcn_exp2f(x);
#else
    return __expf(x * 0.6931471805599453f);
#endif
}

__device__ __forceinline__ void gload_lds16(const bf16_t* g, bf16_t* l) {
    __builtin_amdgcn_global_load_lds(
        (const __attribute__((address_space(1))) void*)g,
        (__attribute__((address_space(3))) void*)l, 16, 0, 0);
}

// ---------------------------------------------------------------- casts
__global__ __launch_bounds__(256)
void cast_f32_bf16(const float* __restrict__ in, bf16_t* __restrict__ out, int n8) {
    int i = blockIdx.x * 256 + threadIdx.x;
    if (i >= n8) return;
    const float4* p = (const float4*)in;
    float4 a = p[i * 2], b = p[i * 2 + 1];
    bf16x8 o;
    o[0] = (bf16_t)a.x; o[1] = (bf16_t)a.y; o[2] = (bf16_t)a.z; o[3] = (bf16_t)a.w;
    o[4] = (bf16_t)b.x; o[5] = (bf16_t)b.y; o[6] = (bf16_t)b.z; o[7] = (bf16_t)b.w;
    *(bf16x8*)(out + (size_t)i * 8) = o;
}

__global__ __launch_bounds__(256)
void cast4_f32_bf16(const float* __restrict__ i0, const float* __restrict__ i1,
                    const float* __restrict__ i2, const float* __restrict__ i3,
                    bf16_t* o0, bf16_t* o1, bf16_t* o2, bf16_t* o3, int n8) {
    const float* in = blockIdx.y == 0 ? i0 : blockIdx.y == 1 ? i1 : blockIdx.y == 2 ? i2 : i3;
    bf16_t*     out = blockIdx.y == 0 ? o0 : blockIdx.y == 1 ? o1 : blockIdx.y == 2 ? o2 : o3;
    int i = blockIdx.x * 256 + threadIdx.x;
    if (i >= n8) return;
    const float4* p = (const float4*)in;
    float4 a = p[i * 2], b = p[i * 2 + 1];
    bf16x8 o;
    o[0] = (bf16_t)a.x; o[1] = (bf16_t)a.y; o[2] = (bf16_t)a.z; o[3] = (bf16_t)a.w;
    o[4] = (bf16_t)b.x; o[5] = (bf16_t)b.y; o[6] = (bf16_t)b.z; o[7] = (bf16_t)b.w;
    *(bf16x8*)(out + (size_t)i * 8) = o;
}

// ---------------------------------------------------------------- GEMM (C = A * B^T)
template<int OUT_BF16>
__global__ __launch_bounds__(256)
void gemm_bt(const bf16_t* __restrict__ A, const bf16_t* __restrict__ B,
             void* __restrict__ Cv, int M, int N, int K) {
    __shared__ bf16_t As[128 * 32];
    __shared__ bf16_t Bs[128 * 32];
    const int tid = threadIdx.x;
    const int lane = tid & 63;
    const int w = tid >> 6;
    const int wm = w >> 1, wn = w & 1;
    const int g = lane >> 4, c = lane & 15;
    const long bm = (long)blockIdx.x * 128;
    const long bn = (long)blockIdx.y * 128;

    f32x4 acc[4][4] = {};

    const int srow = tid >> 2;
    const int scol = (tid & 3) << 3;
    const bf16_t* Ag = A + (bm + srow) * (long)K + scol;
    const bf16_t* Bg = B + (bn + srow) * (long)K + scol;
    bf16_t* AsW = As + tid * 8;
    bf16_t* BsW = Bs + tid * 8;

    for (int k0 = 0; k0 < K; k0 += 32) {
        gload_lds16(Ag + k0,                 AsW);
        gload_lds16(Ag + k0 + (long)64 * K,  AsW + 2048);
        gload_lds16(Bg + k0,                 BsW);
        gload_lds16(Bg + k0 + (long)64 * K,  BsW + 2048);
        __syncthreads();
        bf16x8 af[4], bfr[4];
        #pragma unroll
        for (int m = 0; m < 4; ++m)
            af[m] = *(const bf16x8*)(As + (wm * 64 + m * 16 + c) * 32 + g * 8);
        #pragma unroll
        for (int n = 0; n < 4; ++n)
            bfr[n] = *(const bf16x8*)(Bs + (wn * 64 + n * 16 + c) * 32 + g * 8);
        #pragma unroll
        for (int m = 0; m < 4; ++m)
            #pragma unroll
            for (int n = 0; n < 4; ++n)
                acc[m][n] = MFMA16(af[m], bfr[n], acc[m][n]);
        __syncthreads();
    }
    #pragma unroll
    for (int m = 0; m < 4; ++m)
        #pragma unroll
        for (int n = 0; n < 4; ++n)
            #pragma unroll
            for (int i = 0; i < 4; ++i) {
                long row = bm + wm * 64 + m * 16 + g * 4 + i;
                long col = bn + wn * 64 + n * 16 + c;
                float v = acc[m][n][i];
                if (OUT_BF16) ((bf16_t*)Cv)[row * N + col] = (bf16_t)v;
                else          ((float*)Cv)[row * N + col]  = v;
            }
}

// ---------------------------------------------------------------- flash attention
// grid: (64=B*H, 8), block 512 (8 waves x 16 q-rows = 128 q-rows). Each block
// does q-tiles {bx, 15-bx} (uniform 34 kv-tiles). Swapped QK^T: lane owns one
// q-row (col=c), softmax in-lane, defer-max, P packed b64, PV = mfma(Vt, P).

__device__ __forceinline__ void stage_K(const bf16_t* Kp, long rowb, int kb, int hcol,
                                        bf16_t* Kbuf, int tid) {
    int row = tid >> 3;                       // 0..63
    int lb  = (tid & 7) ^ (row & 7);          // pre-swizzled source -> linear LDS
    gload_lds16(Kp + (rowb + kb + row) * 3072 + hcol + lb * 8, Kbuf + tid * 8);
}

__device__ __forceinline__ void load_V(const bf16_t* Vp, long rowb, int kb, int hcol,
                                       int tid, unsigned int* vr) {
    const int d0 = (tid & 31) * 2;
    const int k0 = (tid >> 5) * 4;
    const unsigned int* src =
        (const unsigned int*)(Vp + (rowb + kb + k0) * 3072 + hcol + d0);
    #pragma unroll
    for (int i = 0; i < 4; ++i) vr[i] = src[(size_t)i * 1536];
}

__device__ __forceinline__ void write_Vt(bf16_t* Vbuf, int tid, const unsigned int* vr) {
    const int d0 = (tid & 31) * 2;
    const int k0 = (tid >> 5) * 4;
    unsigned int lo[2], hi[2];
    #pragma unroll
    for (int i = 0; i < 2; ++i) {
        lo[i] = (vr[2 * i] & 0xffffu) | (vr[2 * i + 1] << 16);
        hi[i] = (vr[2 * i] >> 16)     | (vr[2 * i + 1] & 0xffff0000u);
    }
    *(uint2*)&Vbuf[(d0 + 0) * 72 + k0] = make_uint2(lo[0], lo[1]);
    *(uint2*)&Vbuf[(d0 + 1) * 72 + k0] = make_uint2(hi[0], hi[1]);
}

__global__ __launch_bounds__(512, 4)
void attn_kernel(const bf16_t* __restrict__ Qp, const bf16_t* __restrict__ Kp,
                 const bf16_t* __restrict__ Vp, bf16_t* __restrict__ O) {
    __shared__ bf16_t Ks[2][64 * 64];    // K[key][d], d-blocks XOR-swizzled by key&7
    __shared__ bf16_t Vts[2][64 * 72];   // V^T[d][key], stride 72
    __shared__ bf16_t PW[8][16 * 72];    // per-wave P[q][key], stride 72

    const int tid = threadIdx.x, lane = tid & 63, w = tid >> 6;
    const int g = lane >> 4, c = lane & 15;
    const int bh = blockIdx.x, bx = blockIdx.y;   // same-bh blocks share XCD (id%8)
    const int b = bh >> 4, h = bh & 15;
    const long rowb = (long)b * 2048;
    const int hcol = h * 64;
    const float QSCL = 0.18033688011112042f;      // 0.125 * log2(e)

    for (int pass = 0; pass < 2; ++pass) {
        const int q0  = pass ? (15 - bx) : bx;
        const int qlo = q0 * 128 + w * 16;        // this wave's 16 q-rows
        const int nkt = 2 * q0 + 2;

        // Q as B-fragments: lane holds Q[q = qlo+c][k = ks*32+g*8+j]
        bf16x8 qf[2];
        #pragma unroll
        for (int ks = 0; ks < 2; ++ks) {
            qf[ks] = *(const bf16x8*)(Qp + (rowb + qlo + c) * 3072 +
                                      hcol + ks * 32 + g * 8);
            #pragma unroll
            for (int j = 0; j < 8; ++j)
                qf[ks][j] = (bf16_t)((float)qf[ks][j] * QSCL);
        }

        float m_r = -1e30f, l_r = 0.f;
        f32x4 acc[4] = {};                        // O^T: [d-blk nt], rows g*4+i, col q=c

        stage_K(Kp, rowb, 0, hcol, Ks[0], tid);
        {
            unsigned int vr0[4];
            load_V(Vp, rowb, 0, hcol, tid, vr0);
            write_Vt(Vts[0], tid, vr0);
        }
        __syncthreads();

        for (int t = 0; t < nkt; ++t) {
            const int cur = t & 1;
            const int kb = t * 64;
            const bool pre = (t + 1 < nkt);
            unsigned int vr[4];
            if (pre) {
                stage_K(Kp, rowb, kb + 64, hcol, Ks[cur ^ 1], tid);
                load_V(Vp, rowb, kb + 64, hcol, tid, vr);
            }

            if (kb <= qlo + 15) {                 // skip fully-masked tiles (per-wave)
                // --- S^T = K Q^T: rows key = nt*16+g*4+i, col q = c
                f32x4 sacc[4] = {};
                #pragma unroll
                for (int nt = 0; nt < 4; ++nt) {
                    const int row = nt * 16 + c;
                    #pragma unroll
                    for (int ks = 0; ks < 2; ++ks) {
                        bf16x8 kf = *(const bf16x8*)&Ks[cur][row * 64 +
                                        (((ks * 4 + g) ^ (c & 7)) * 8)];
                        sacc[nt] = MFMA16(kf, qf[ks], sacc[nt]);
                    }
                }
                if (kb + 63 > qlo) {              // diagonal: causal mask
                    const int q = qlo + c;
                    #pragma unroll
                    for (int nt = 0; nt < 4; ++nt)
                        #pragma unroll
                        for (int i = 0; i < 4; ++i) {
                            int key = kb + nt * 16 + g * 4 + i;
                            if (key > q) sacc[nt][i] = -1e30f;
                        }
                }

                // --- online softmax with defer-max (THR=8 in log2 units)
                float mx = sacc[0][0];
                #pragma unroll
                for (int nt = 0; nt < 4; ++nt)
                    #pragma unroll
                    for (int i = 0; i < 4; ++i)
                        mx = fmaxf(mx, sacc[nt][i]);
                mx = fmaxf(mx, __shfl_xor(mx, 16, 64));
                mx = fmaxf(mx, __shfl_xor(mx, 32, 64));
                if (__any(mx > m_r + 8.f)) {      // rescale only on real max growth
                    float mnew = fmaxf(m_r, mx);
                    float scl = exp2_(m_r - mnew);
                    #pragma unroll
                    for (int nt = 0; nt < 4; ++nt)
                        acc[nt] *= scl;
                    l_r *= scl;
                    m_r = mnew;
                }
                float rs = 0.f;
                #pragma unroll
                for (int nt = 0; nt < 4; ++nt)
                    #pragma unroll
                    for (int i = 0; i < 4; ++i) {
                        float pv = exp2_(sacc[nt][i] - m_r);
                        sacc[nt][i] = pv;
                        rs += pv;
                    }
                rs += __shfl_xor(rs, 16, 64);
                rs += __shfl_xor(rs, 32, 64);
                l_r += rs;

                // --- P pack: lane holds 4 consecutive keys -> one b64 per nt
                #pragma unroll
                for (int nt = 0; nt < 4; ++nt) {
                    bf16x4 t4;
                    #pragma unroll
                    for (int i = 0; i < 4; ++i) t4[i] = (bf16_t)sacc[nt][i];
                    *(bf16x4*)&PW[w][c * 72 + nt * 16 + g * 4] = t4;
                }

                // --- PV: O^T += V^T P^T (A = V^T frag, B = P frag, wave-private)
                #pragma unroll
                for (int ks = 0; ks < 2; ++ks) {
                    bf16x8 pf = *(const bf16x8*)&PW[w][c * 72 + ks * 32 + g * 8];
                    #pragma unroll
                    for (int nt = 0; nt < 4; ++nt) {
                        bf16x8 vf = *(const bf16x8*)&Vts[cur][(nt * 16 + c) * 72 +
                                                              ks * 32 + g * 8];
                        acc[nt] = MFMA16(vf, pf, acc[nt]);
                    }
                }
            }

            if (pre) write_Vt(Vts[cur ^ 1], tid, vr);   // write-late (T14)
            __syncthreads();                             // single barrier per tile
        }

        // --- epilogue: O^T -> (wave-private LDS transpose) coalesced O rows
        {
            float rl = __builtin_amdgcn_rcpf(l_r);
            #pragma unroll
            for (int nt = 0; nt < 4; ++nt) {
                bf16x4 t4;
                #pragma unroll
                for (int i = 0; i < 4; ++i) t4[i] = (bf16_t)(acc[nt][i] * rl);
                *(bf16x4*)&PW[w][c * 72 + nt * 16 + g * 4] = t4;
            }
        }
        #pragma unroll
        for (int p = 0; p < 2; ++p) {
            int row = p * 8 + (lane >> 3);
            int ch  = (lane & 7) * 8;
            bf16x8 v = *(const bf16x8*)&PW[w][row * 72 + ch];
            *(bf16x8*)&O[(rowb + qlo + row) * 1024 + hcol + ch] = v;
        }
    }
}

// ---------------------------------------------------------------- launch
extern "C" void kernel_launch(void* const* d_in, const int* in_sizes, int n_in,
                              void* d_out, int out_size, void* d_ws, size_t ws_size,
                              hipStream_t stream) {
    const float* x  = (const float*)d_in[0];
    const float* Wq = (const float*)d_in[1];
    const float* Wk = (const float*)d_in[2];
    const float* Wv = (const float*)d_in[3];
    const float* Wo = (const float*)d_in[4];

    const int M = 8192;
    const int C = 1024;

    char* ws = (char*)d_ws;
    bf16_t* xb   = (bf16_t*)(ws);                          // 16 MB
    bf16_t* wqkv = (bf16_t*)(ws + ((size_t)16 << 20));     //  6 MB ([3072][1024])
    bf16_t* wob  = (bf16_t*)(ws + ((size_t)22 << 20));     //  2 MB
    bf16_t* qkv  = (bf16_t*)(ws + ((size_t)24 << 20));     // 48 MB ([8192][3072])
    bf16_t* aob  = (bf16_t*)(ws + ((size_t)72 << 20));     // 16 MB ([8192][1024])

    cast_f32_bf16<<<(M * C / 8) / 256, 256, 0, stream>>>(x, xb, M * C / 8);
    cast4_f32_bf16<<<dim3((C * C / 8) / 256, 4), 256, 0, stream>>>(
        Wq, Wk, Wv, Wo,
        wqkv, wqkv + (size_t)(C * C), wqkv + (size_t)(2 * C * C), wob, C * C / 8);

    gemm_bt<1><<<dim3(M / 128, 3072 / 128), 256, 0, stream>>>(xb, wqkv, qkv, M, 3072, C);

    attn_kernel<<<dim3(64, 8), 512, 0, stream>>>(
        qkv, qkv + 1024, qkv + 2048, aob);

    gemm_bt<0><<<dim3(M / 128, C / 128), 256, 0, stream>>>(aob, wob, d_out, M, C, C);
}